// Round 3
// baseline (541.989 us; speedup 1.0000x reference)
//
#include <hip/hip_runtime.h>
#include <hip/hip_bf16.h>
#include <math.h>

typedef float f32x4 __attribute__((ext_vector_type(4)));
typedef short bf16x8 __attribute__((ext_vector_type(8)));

#define H_DIM 4096
#define E_EXP 64
#define NTOK  16384
#define PLANE (E_EXP * H_DIM)      // shorts per w plane = 262144
#define PS    132                  // floats per block partial: 64 psum + 64 cnt + 1 z
#define NB2   1024                 // main-kernel blocks (16 tokens each)

// split fp32 -> h + m + l (bf16 each), residual ~2^-27|v|
__device__ __forceinline__ void split8(f32x4 a, f32x4 b, bf16x8 &h, bf16x8 &m, bf16x8 &l){
#pragma unroll
    for (int j = 0; j < 8; j++){
        float v = (j < 4) ? a[j] : b[j - 4];
        __hip_bfloat16 hb = __float2bfloat16(v);
        float r1 = v - __bfloat162float(hb);
        __hip_bfloat16 mb = __float2bfloat16(r1);
        float r2 = r1 - __bfloat162float(mb);
        __hip_bfloat16 lb = __float2bfloat16(r2);
        h[j] = __builtin_bit_cast(short, hb);
        m[j] = __builtin_bit_cast(short, mb);
        l[j] = __builtin_bit_cast(short, lb);
    }
}

#define MFMA __builtin_amdgcn_mfma_f32_16x16x32_bf16

// ---------------------------------------------------------------------------
// Kernel A: pre-split gate_w into 3 bf16 planes [3][E][H] (1.5 MB, L2-resident)
// ---------------------------------------------------------------------------
__global__ __launch_bounds__(256) void moe_wsplit(
    const float* __restrict__ gw, short* __restrict__ wpl)
{
    const int idx = (blockIdx.x * 256 + threadIdx.x) * 8;   // 128 blocks cover 262144
    f32x4 a = *(const f32x4*)(gw + idx);
    f32x4 b = *(const f32x4*)(gw + idx + 4);
    bf16x8 h, m, l; split8(a, b, h, m, l);
    *(bf16x8*)(wpl + idx)             = h;
    *(bf16x8*)(wpl + PLANE + idx)     = m;
    *(bf16x8*)(wpl + 2 * PLANE + idx) = l;
}

// ---------------------------------------------------------------------------
// Main: 1024 blocks x 256 threads. Block owns 16 tokens; wave wv does K-chunk
// range [32wv, 32wv+32). Barrier-free K-loop: x split in-reg, w frags direct
// from pre-split global planes. LDS reduce of 4 partial C-frags, fused epilogue.
// ---------------------------------------------------------------------------
__global__ __launch_bounds__(256) void moe_gate_main(
    const float* __restrict__ x, const short* __restrict__ wpl,
    const float* __restrict__ bias, float* __restrict__ out,
    float* __restrict__ part)
{
    __shared__ f32x4 red[4][4][64];       // [wave][expert-group][lane]
    __shared__ float ls[16 * 68];         // logits/probs [token][expert], padded
    __shared__ float bs[64], rs[16];
    __shared__ int   ia[16], ib[16];

    const int tid = threadIdx.x, bid = blockIdx.x;
    const int wv = tid >> 6, l = tid & 63, l16 = l & 15, lk = l >> 4;
    const int tok0 = bid * 16;

    if (tid < 64) bs[tid] = bias[tid];

    const float* xp = x   + (size_t)(tok0 + l16) * H_DIM + wv * 1024 + lk * 8;
    const short* wp = wpl + l16 * H_DIM + wv * 1024 + lk * 8;

    f32x4 acc[4] = {};

    f32x4 xa = *(const f32x4*)xp;
    f32x4 xb = *(const f32x4*)(xp + 4);

    for (int cc = 0; cc < 32; ++cc){
        bf16x8 xh, xm, xl; split8(xa, xb, xh, xm, xl);
        if (cc < 31){
            xa = *(const f32x4*)(xp + (cc + 1) * 32);
            xb = *(const f32x4*)(xp + (cc + 1) * 32 + 4);
        }
        bf16x8 wf[4][3];
#pragma unroll
        for (int g = 0; g < 4; ++g){
            const short* wpg = wp + g * 16 * H_DIM + cc * 32;
#pragma unroll
            for (int p = 0; p < 3; ++p)
                wf[g][p] = *(const bf16x8*)(wpg + p * PLANE);
        }
#pragma unroll
        for (int g = 0; g < 4; ++g){
            acc[g] = MFMA(xh, wf[g][0], acc[g], 0, 0, 0);
            acc[g] = MFMA(xm, wf[g][0], acc[g], 0, 0, 0);
            acc[g] = MFMA(xh, wf[g][1], acc[g], 0, 0, 0);
            acc[g] = MFMA(xm, wf[g][1], acc[g], 0, 0, 0);
            acc[g] = MFMA(xh, wf[g][2], acc[g], 0, 0, 0);
            acc[g] = MFMA(xl, wf[g][0], acc[g], 0, 0, 0);
        }
    }

    // ---- reduce 4 K-partials -> logits in LDS ----
#pragma unroll
    for (int g = 0; g < 4; ++g) red[wv][g][l] = acc[g];
    __syncthreads();
    {
        const int g = tid >> 6, ll = tid & 63;
        f32x4 s = red[0][g][ll];
#pragma unroll
        for (int w2 = 1; w2 < 4; ++w2) s += red[w2][g][ll];
        const int l16b = ll & 15, lkb = ll >> 4;
#pragma unroll
        for (int r = 0; r < 4; ++r)
            ls[(lkb * 4 + r) * 68 + g * 16 + l16b] = s[r];
    }
    __syncthreads();

    // ---- epilogue: wave 0 only. lane = token*4 + sub; sub owns 16 experts ----
    if (tid < 64){
        const int t = tid >> 2, s4 = tid & 3, eb = s4 * 16;
        const float invTemp = (1.0f / 3.0f);
        float m1 = -1e30f, m2 = -1e30f; int i1 = 0, i2 = 0;
        for (int j = 0; j < 16; ++j){
            const int e = eb + j;
            float v = (ls[t * 68 + e] + bs[e]) * invTemp;
            ls[t * 68 + e] = v;
            if (v > m1)      { m2 = m1; i2 = i1; m1 = v; i1 = e; }
            else if (v > m2) { m2 = v;  i2 = e; }
        }
        // merge top-2 across the 4-lane quad (lowest index wins ties)
#pragma unroll
        for (int off = 1; off <= 2; off <<= 1){
            float om1 = __shfl_xor(m1, off), om2 = __shfl_xor(m2, off);
            int   oi1 = __shfl_xor(i1, off), oi2 = __shfl_xor(i2, off);
            bool sw = (om1 > m1) || (om1 == m1 && oi1 < i1);
            float n1 = sw ? om1 : m1;  int ni1 = sw ? oi1 : i1;
            float lm = sw ? m1  : om1; int li  = sw ? i1  : oi1;
            float w2 = sw ? om2 : m2;  int wi  = sw ? oi2 : i2;
            bool s2 = (lm > w2) || (lm == w2 && li < wi);
            m1 = n1; i1 = ni1;
            m2 = s2 ? lm : w2; i2 = s2 ? li : wi;
        }
        float ssum = 0.f;
        for (int j = 0; j < 16; ++j){
            const int e = eb + j;
            float p = __expf(ls[t * 68 + e] - m1);
            ls[t * 68 + e] = p;
            ssum += p;
        }
        ssum += __shfl_xor(ssum, 1);
        ssum += __shfl_xor(ssum, 2);

        float zsq = 0.f;
        if (s4 == 0){
            rs[t] = 1.0f / ssum; ia[t] = i1; ib[t] = i2;
            float p2    = __expf(m2 - m1);
            float inv12 = 1.0f / (1.0f + p2);
            out[(size_t)(tok0 + t) * 2 + 0] = inv12;
            out[(size_t)(tok0 + t) * 2 + 1] = p2 * inv12;
            out[(size_t)NTOK * 2 + (size_t)(tok0 + t) * 2 + 0] = (float)i1;
            out[(size_t)NTOK * 2 + (size_t)(tok0 + t) * 2 + 1] = (float)i2;
            float lse = m1 + logf(ssum);
            zsq = lse * lse;
        }
#pragma unroll
        for (int o = 32; o; o >>= 1) zsq += __shfl_xor(zsq, o);

        // per-expert block partials: lane = expert
        float psum = 0.f, csum = 0.f;
        for (int t2 = 0; t2 < 16; ++t2){
            psum += ls[t2 * 68 + tid] * rs[t2];
            csum += (ia[t2] == tid ? 1.f : 0.f) + (ib[t2] == tid ? 1.f : 0.f);
        }
        part[bid * PS + tid]      = psum;
        part[bid * PS + 64 + tid] = csum;
        if (tid == 0) part[bid * PS + 128] = zsq;
    }
}

// ---------------------------------------------------------------------------
// Loss reduction over NB2=1024 block partials
// ---------------------------------------------------------------------------
__global__ __launch_bounds__(1024) void moe_gate_loss(
    const float* __restrict__ part, float* __restrict__ out)
{
    __shared__ float spS[16][64], scS[16][64], zW[16];
    const int tid = threadIdx.x;
    const int e = tid & 63, g = tid >> 6;
    float sp = 0.f, sc = 0.f;
    for (int b = g; b < NB2; b += 16){
        sp += part[b * PS + e];
        sc += part[b * PS + 64 + e];
    }
    spS[g][e] = sp; scS[g][e] = sc;
    float z = part[tid * PS + 128];
#pragma unroll
    for (int o = 32; o; o >>= 1) z += __shfl_xor(z, o);
    if ((tid & 63) == 0) zW[g] = z;
    __syncthreads();

    if (tid < 64){
        float tsp = 0.f, tsc = 0.f;
#pragma unroll
        for (int q = 0; q < 16; ++q){ tsp += spS[q][tid]; tsc += scS[q][tid]; }
        float zp = (tid < 16) ? zW[tid] : 0.f;
        const float invN = 1.0f / (float)NTOK;
        float dot = (tsc * invN) * (tsp * invN);
#pragma unroll
        for (int o = 32; o; o >>= 1){
            dot += __shfl_xor(dot, o);
            zp  += __shfl_xor(zp, o);
        }
        if (tid == 0)
            out[(size_t)NTOK * 4] = 0.01f * 64.0f * dot + 1e-4f * zp * invN;
    }
}

// ---------------------------------------------------------------------------
extern "C" void kernel_launch(void* const* d_in, const int* in_sizes, int n_in,
                              void* d_out, int out_size, void* d_ws, size_t ws_size,
                              hipStream_t stream)
{
    const float* x    = (const float*)d_in[0];
    const float* gw   = (const float*)d_in[1];
    const float* bias = (const float*)d_in[2];
    float* out = (float*)d_out;

    short* wpl = (short*)d_ws;                                   // 3*PLANE shorts = 1.5 MB
    float* part = (float*)((char*)d_ws + 3 * PLANE * sizeof(short)); // NB2*PS floats = 540 KB

    moe_wsplit<<<128, 256, 0, stream>>>(gw, wpl);
    moe_gate_main<<<NB2, 256, 0, stream>>>(x, wpl, bias, out, part);
    moe_gate_loss<<<1, 1024, 0, stream>>>(part, out);
}

// Round 5
// 443.548 us; speedup vs baseline: 1.2219x; 1.2219x over previous
//
#include <hip/hip_runtime.h>
#include <hip/hip_bf16.h>
#include <math.h>

typedef float f32x4 __attribute__((ext_vector_type(4)));
typedef short bf16x8 __attribute__((ext_vector_type(8)));

#define H_DIM 4096
#define E_EXP 64
#define NTOK  16384
#define PLANE (E_EXP * H_DIM)      // shorts per w plane = 262144
#define PS    132                  // floats per block partial: 64 psum + 64 cnt + 1 z
#define NBLK  512                  // main blocks: 32 tokens each

// split fp32 -> h + m + l (bf16 each), residual ~2^-27|v|
__device__ __forceinline__ void split8(f32x4 a, f32x4 b, bf16x8 &h, bf16x8 &m, bf16x8 &l){
#pragma unroll
    for (int j = 0; j < 8; j++){
        float v = (j < 4) ? a[j] : b[j - 4];
        __hip_bfloat16 hb = __float2bfloat16(v);
        float r1 = v - __bfloat162float(hb);
        __hip_bfloat16 mb = __float2bfloat16(r1);
        float r2 = r1 - __bfloat162float(mb);
        __hip_bfloat16 lb = __float2bfloat16(r2);
        h[j] = __builtin_bit_cast(short, hb);
        m[j] = __builtin_bit_cast(short, mb);
        l[j] = __builtin_bit_cast(short, lb);
    }
}

#define MFMA __builtin_amdgcn_mfma_f32_16x16x32_bf16

#define LOADW(W, cc) do {                                                   \
    _Pragma("unroll")                                                       \
    for (int g_ = 0; g_ < 4; g_++){                                         \
        const short* q_ = wp + g_ * 16 * H_DIM + (cc) * 32;                 \
        _Pragma("unroll")                                                   \
        for (int p_ = 0; p_ < 3; p_++)                                      \
            W[g_][p_] = *(const bf16x8*)(q_ + p_ * PLANE);                  \
    } } while(0)

#define DOMFMA(W, H0,M0,L0, H1,M1,L1) do {                                  \
    _Pragma("unroll")                                                       \
    for (int g_ = 0; g_ < 4; g_++){                                         \
        acc[0][g_] = MFMA(H0, W[g_][0], acc[0][g_], 0, 0, 0);               \
        acc[0][g_] = MFMA(M0, W[g_][0], acc[0][g_], 0, 0, 0);               \
        acc[0][g_] = MFMA(H0, W[g_][1], acc[0][g_], 0, 0, 0);               \
        acc[0][g_] = MFMA(M0, W[g_][1], acc[0][g_], 0, 0, 0);               \
        acc[0][g_] = MFMA(H0, W[g_][2], acc[0][g_], 0, 0, 0);               \
        acc[0][g_] = MFMA(L0, W[g_][0], acc[0][g_], 0, 0, 0);               \
        acc[1][g_] = MFMA(H1, W[g_][0], acc[1][g_], 0, 0, 0);               \
        acc[1][g_] = MFMA(M1, W[g_][0], acc[1][g_], 0, 0, 0);               \
        acc[1][g_] = MFMA(H1, W[g_][1], acc[1][g_], 0, 0, 0);               \
        acc[1][g_] = MFMA(M1, W[g_][1], acc[1][g_], 0, 0, 0);               \
        acc[1][g_] = MFMA(H1, W[g_][2], acc[1][g_], 0, 0, 0);               \
        acc[1][g_] = MFMA(L1, W[g_][0], acc[1][g_], 0, 0, 0);               \
    } } while(0)

// ---------------------------------------------------------------------------
// Kernel A: pre-split gate_w into 3 bf16 planes [3][E][H] (1.5 MB, L2-resident)
// ---------------------------------------------------------------------------
__global__ __launch_bounds__(256) void moe_wsplit(
    const float* __restrict__ gw, short* __restrict__ wpl)
{
    const int idx = (blockIdx.x * 256 + threadIdx.x) * 8;
    f32x4 a = *(const f32x4*)(gw + idx);
    f32x4 b = *(const f32x4*)(gw + idx + 4);
    bf16x8 h, m, l; split8(a, b, h, m, l);
    *(bf16x8*)(wpl + idx)             = h;
    *(bf16x8*)(wpl + PLANE + idx)     = m;
    *(bf16x8*)(wpl + 2 * PLANE + idx) = l;
}

// ---------------------------------------------------------------------------
// Main: 512 blocks x 256 threads. Block owns 32 tokens; wave wv owns K-range
// [1024*wv, +1024) (32 chunks of 32). Barrier-free K-loop, explicit
// double-buffered w fragments, 2 A-frags/wave (48 MFMA per chunk).
// ---------------------------------------------------------------------------
__global__ __launch_bounds__(256, 2) void moe_gate_main(
    const float* __restrict__ x, const short* __restrict__ wpl,
    const float* __restrict__ bias, float* __restrict__ out,
    float* __restrict__ part)
{
    __shared__ f32x4 red[4][2][4][64];    // [wave][frag][expert-group][lane]
    __shared__ float ls[32 * 68];         // logits/probs [token][expert], padded
    __shared__ float bs[64], rs[32], zW[2];
    __shared__ int   ia[32], ib[32];

    const int tid = threadIdx.x, bid = blockIdx.x;
    const int wv = tid >> 6, l = tid & 63, l16 = l & 15, lk = l >> 4;
    const int tok0 = bid * 32;

    if (tid < 64) bs[tid] = bias[tid];

    const float* xp0 = x + (size_t)(tok0 + l16) * H_DIM + wv * 1024 + lk * 8;
    const float* xp1 = xp0 + 16 * H_DIM;
    const short* wp  = wpl + l16 * H_DIM + wv * 1024 + lk * 8;

    f32x4 acc[2][4] = {};

    bf16x8 wA[4][3], wB[4][3];
    LOADW(wA, 0);
    f32x4 ea0 = *(const f32x4*)xp0,        eb0 = *(const f32x4*)(xp0 + 4);
    f32x4 ea1 = *(const f32x4*)xp1,        eb1 = *(const f32x4*)(xp1 + 4);
    f32x4 oa0 = *(const f32x4*)(xp0 + 32), ob0 = *(const f32x4*)(xp0 + 36);
    f32x4 oa1 = *(const f32x4*)(xp1 + 32), ob1 = *(const f32x4*)(xp1 + 36);

    for (int cp = 0; cp < 16; cp++){
        const int c0 = 2 * cp;
        // ---- even phase: chunk c0 on wA; prefetch wB(c0+1), x(c0+2) ----
        {
            LOADW(wB, c0 + 1);
            bf16x8 h0, m0, l0, h1, m1, l1;
            split8(ea0, eb0, h0, m0, l0);
            split8(ea1, eb1, h1, m1, l1);
            if (cp < 15){
                ea0 = *(const f32x4*)(xp0 + (c0 + 2) * 32);
                eb0 = *(const f32x4*)(xp0 + (c0 + 2) * 32 + 4);
                ea1 = *(const f32x4*)(xp1 + (c0 + 2) * 32);
                eb1 = *(const f32x4*)(xp1 + (c0 + 2) * 32 + 4);
            }
            DOMFMA(wA, h0, m0, l0, h1, m1, l1);
        }
        // ---- odd phase: chunk c0+1 on wB; prefetch wA(c0+2), x(c0+3) ----
        {
            if (cp < 15) LOADW(wA, c0 + 2);
            bf16x8 h0, m0, l0, h1, m1, l1;
            split8(oa0, ob0, h0, m0, l0);
            split8(oa1, ob1, h1, m1, l1);
            if (cp < 15){
                oa0 = *(const f32x4*)(xp0 + (c0 + 3) * 32);
                ob0 = *(const f32x4*)(xp0 + (c0 + 3) * 32 + 4);
                oa1 = *(const f32x4*)(xp1 + (c0 + 3) * 32);
                ob1 = *(const f32x4*)(xp1 + (c0 + 3) * 32 + 4);
            }
            DOMFMA(wB, h0, m0, l0, h1, m1, l1);
        }
    }

    // ---- reduce 4 K-partials -> logits LDS ----
#pragma unroll
    for (int f = 0; f < 2; f++)
#pragma unroll
        for (int g = 0; g < 4; g++) red[wv][f][g][l] = acc[f][g];
    __syncthreads();
    {
        const int g2 = tid >> 6, l2 = tid & 63;
        const int l16b = l2 & 15, lkb = l2 >> 4;
#pragma unroll
        for (int f = 0; f < 2; f++){
            f32x4 s = red[0][f][g2][l2];
#pragma unroll
            for (int w2 = 1; w2 < 4; ++w2) s += red[w2][f][g2][l2];
#pragma unroll
            for (int r = 0; r < 4; ++r)
                ls[(f * 16 + lkb * 4 + r) * 68 + g2 * 16 + l16b] = s[r];
        }
    }
    __syncthreads();

    // ---- epilogue: 2 waves, 4 lanes/token (16 experts each) ----
    if (tid < 128){
        const int t = tid >> 2, s4 = tid & 3, eb = s4 * 16;
        const float invTemp = (1.0f / 3.0f);
        float m1 = -1e30f, m2 = -1e30f; int i1 = 0, i2 = 0;
        for (int j = 0; j < 16; ++j){
            const int e = eb + j;
            float v = (ls[t * 68 + e] + bs[e]) * invTemp;
            ls[t * 68 + e] = v;
            if (v > m1)      { m2 = m1; i2 = i1; m1 = v; i1 = e; }
            else if (v > m2) { m2 = v;  i2 = e; }
        }
#pragma unroll
        for (int off = 1; off <= 2; off <<= 1){
            float om1 = __shfl_xor(m1, off), om2 = __shfl_xor(m2, off);
            int   oi1 = __shfl_xor(i1, off), oi2 = __shfl_xor(i2, off);
            bool sw = (om1 > m1) || (om1 == m1 && oi1 < i1);
            float n1 = sw ? om1 : m1;  int ni1 = sw ? oi1 : i1;
            float lm = sw ? m1  : om1; int li  = sw ? i1  : oi1;
            float w2 = sw ? om2 : m2;  int wi  = sw ? oi2 : i2;
            bool s2 = (lm > w2) || (lm == w2 && li < wi);
            m1 = n1; i1 = ni1;
            m2 = s2 ? lm : w2; i2 = s2 ? li : wi;
        }
        float ssum = 0.f;
        for (int j = 0; j < 16; ++j){
            const int e = eb + j;
            float p = __expf(ls[t * 68 + e] - m1);
            ls[t * 68 + e] = p;
            ssum += p;
        }
        ssum += __shfl_xor(ssum, 1);
        ssum += __shfl_xor(ssum, 2);

        float zsq = 0.f;
        if (s4 == 0){
            rs[t] = 1.0f / ssum; ia[t] = i1; ib[t] = i2;
            float p2    = __expf(m2 - m1);
            float inv12 = 1.0f / (1.0f + p2);
            out[(size_t)(tok0 + t) * 2 + 0] = inv12;
            out[(size_t)(tok0 + t) * 2 + 1] = p2 * inv12;
            out[(size_t)NTOK * 2 + (size_t)(tok0 + t) * 2 + 0] = (float)i1;
            out[(size_t)NTOK * 2 + (size_t)(tok0 + t) * 2 + 1] = (float)i2;
            float lse = m1 + logf(ssum);
            zsq = lse * lse;
        }
#pragma unroll
        for (int o = 32; o; o >>= 1) zsq += __shfl_xor(zsq, o);
        if ((tid & 63) == 0) zW[tid >> 6] = zsq;
    }
    __syncthreads();

    // ---- per-expert block partials: lane = expert ----
    if (tid < 64){
        float psum = 0.f, csum = 0.f;
        for (int t2 = 0; t2 < 32; ++t2){
            psum += ls[t2 * 68 + tid] * rs[t2];
            csum += (ia[t2] == tid ? 1.f : 0.f) + (ib[t2] == tid ? 1.f : 0.f);
        }
        part[bid * PS + tid]      = psum;
        part[bid * PS + 64 + tid] = csum;
        if (tid == 0) part[bid * PS + 128] = zW[0] + zW[1];
    }
}

// ---------------------------------------------------------------------------
// Loss reduction over NBLK=512 block partials
// ---------------------------------------------------------------------------
__global__ __launch_bounds__(1024) void moe_gate_loss(
    const float* __restrict__ part, float* __restrict__ out)
{
    __shared__ float spS[16][64], scS[16][64], zW[16];
    const int tid = threadIdx.x;
    const int e = tid & 63, g = tid >> 6;
    float sp = 0.f, sc = 0.f;
    for (int b = g; b < NBLK; b += 16){
        sp += part[b * PS + e];
        sc += part[b * PS + 64 + e];
    }
    spS[g][e] = sp; scS[g][e] = sc;
    float z = (tid < NBLK) ? part[tid * PS + 128] : 0.f;
#pragma unroll
    for (int o = 32; o; o >>= 1) z += __shfl_xor(z, o);
    if ((tid & 63) == 0) zW[g] = z;
    __syncthreads();

    if (tid < 64){
        float tsp = 0.f, tsc = 0.f;
#pragma unroll
        for (int q = 0; q < 16; ++q){ tsp += spS[q][tid]; tsc += scS[q][tid]; }
        float zp = (tid < 16) ? zW[tid] : 0.f;
        const float invN = 1.0f / (float)NTOK;
        float dot = (tsc * invN) * (tsp * invN);
#pragma unroll
        for (int o = 32; o; o >>= 1){
            dot += __shfl_xor(dot, o);
            zp  += __shfl_xor(zp, o);
        }
        if (tid == 0)
            out[(size_t)NTOK * 4] = 0.01f * 64.0f * dot + 1e-4f * zp * invN;
    }
}

// ---------------------------------------------------------------------------
extern "C" void kernel_launch(void* const* d_in, const int* in_sizes, int n_in,
                              void* d_out, int out_size, void* d_ws, size_t ws_size,
                              hipStream_t stream)
{
    const float* x    = (const float*)d_in[0];
    const float* gw   = (const float*)d_in[1];
    const float* bias = (const float*)d_in[2];
    float* out = (float*)d_out;

    short* wpl  = (short*)d_ws;                                      // 1.5 MB
    float* part = (float*)((char*)d_ws + 3 * PLANE * sizeof(short)); // 270 KB

    moe_wsplit<<<128, 256, 0, stream>>>(gw, wpl);
    moe_gate_main<<<NBLK, 256, 0, stream>>>(x, wpl, bias, out, part);
    moe_gate_loss<<<1, 1024, 0, stream>>>(part, out);
}

// Round 7
// 415.438 us; speedup vs baseline: 1.3046x; 1.0677x over previous
//
#include <hip/hip_runtime.h>
#include <hip/hip_bf16.h>
#include <math.h>

typedef float f32x4 __attribute__((ext_vector_type(4)));
typedef short bf16x8 __attribute__((ext_vector_type(8)));

#define H_DIM 4096
#define E_EXP 64
#define NTOK  16384
#define PLANE (E_EXP * H_DIM)      // shorts per w plane = 262144
#define PS    132                  // floats per block partial
#define NBLK  256                  // main blocks: 64 tokens each

// split fp32 -> h + m + l (bf16 each), residual ~2^-27|v|
__device__ __forceinline__ void split8(f32x4 a, f32x4 b, bf16x8 &h, bf16x8 &m, bf16x8 &l){
#pragma unroll
    for (int j = 0; j < 8; j++){
        float v = (j < 4) ? a[j] : b[j - 4];
        __hip_bfloat16 hb = __float2bfloat16(v);
        float r1 = v - __bfloat162float(hb);
        __hip_bfloat16 mb = __float2bfloat16(r1);
        float r2 = r1 - __bfloat162float(mb);
        __hip_bfloat16 lb = __float2bfloat16(r2);
        h[j] = __builtin_bit_cast(short, hb);
        m[j] = __builtin_bit_cast(short, mb);
        l[j] = __builtin_bit_cast(short, lb);
    }
}

#define MFMA __builtin_amdgcn_mfma_f32_16x16x32_bf16

__device__ __forceinline__ void gload_lds(const short* g, char* l){
    __builtin_amdgcn_global_load_lds(
        (const __attribute__((address_space(1))) void*)g,
        (__attribute__((address_space(3))) void*)l, 16, 0, 0);
}

// ---------------------------------------------------------------------------
// Kernel A: pre-split gate_w into 3 bf16 planes [3][E][H] (1.5 MB, L2-resident)
// ---------------------------------------------------------------------------
__global__ __launch_bounds__(256) void moe_wsplit(
    const float* __restrict__ gw, short* __restrict__ wpl)
{
    const int idx = (blockIdx.x * 256 + threadIdx.x) * 8;
    f32x4 a = *(const f32x4*)(gw + idx);
    f32x4 b = *(const f32x4*)(gw + idx + 4);
    bf16x8 h, m, l; split8(a, b, h, m, l);
    *(bf16x8*)(wpl + idx)             = h;
    *(bf16x8*)(wpl + PLANE + idx)     = m;
    *(bf16x8*)(wpl + 2 * PLANE + idx) = l;
}

// ---------------------------------------------------------------------------
// Main: 256 blocks x 512 threads (8 waves). Block owns 64 tokens.
// Wave wv: token-group tg=wv&3 (16 tokens), K-half kh=wv>>2 (2048 cols,
// 64 chunks of 32). Per chunk: w staged in LDS via global_load_lds DMA
// (double-buffered, counted vmcnt, raw s_barrier), x split in-register.
// LDS w layout per (kh,buf): [plane(3)][kgrp(4)][expert(64)][8 bf16 = 16B].
// ---------------------------------------------------------------------------
__global__ __launch_bounds__(512, 2) void moe_gate_main(
    const float* __restrict__ x, const short* __restrict__ wpl,
    const float* __restrict__ bias, float* __restrict__ out,
    float* __restrict__ part)
{
    __shared__ short wlds[24576];        // [kh][buf][p][kg][e][8] = 48 KB
    __shared__ f32x4 red[4][4][64];      // kh=1 partials [tg][g][lane] = 16 KB
    __shared__ float ls[64 * 68];        // logits/probs [token][expert]
    __shared__ float bs[64], rs[64], zW[4];
    __shared__ int   ia[64], ib[64];

    const int tid = threadIdx.x, bid = blockIdx.x;
    const int wv = tid >> 6, l = tid & 63, l16 = l & 15, lk = l >> 4;
    const int kh = wv >> 2, tg = wv & 3;
    const int tok0 = bid * 64;

    if (tid < 64) bs[tid] = bias[tid];

    // per-thread staging map: seg = wv*3+i -> (kh_s, plane, kgrp); lane = expert
    const short* wsrc[3]; int wdst[3];
#pragma unroll
    for (int i = 0; i < 3; i++){
        const int sg = wv * 3 + i, khs = sg / 12, r = sg % 12, p = r / 4, kg = r % 4;
        wsrc[i] = wpl + p * PLANE + l * H_DIM + khs * 2048 + kg * 8;
        wdst[i] = khs * 24576 + p * 4096 + kg * 1024;   // bytes; +buf*12288
    }
    // frag-read base (bytes): lane l reads expert g*16+l16, k-slot lk
    const int fb = kh * 24576 + lk * 1024 + l16 * 16;
    // x source: token tok0+tg*16+l16, cols kh*2048 + cc*32 + lk*8
    const float* xbase = x + (size_t)(tok0 + tg * 16 + l16) * H_DIM + kh * 2048 + lk * 8;

    f32x4 acc[4] = {};

#define STAGE(ccn, BUFW) do {                                               \
    __builtin_amdgcn_sched_barrier(0);                                      \
    _Pragma("unroll")                                                       \
    for (int i_ = 0; i_ < 3; i_++)                                          \
        gload_lds(wsrc[i_] + (ccn) * 32,                                    \
                  (char*)wlds + wdst[i_] + (BUFW) * 12288);                 \
    __builtin_amdgcn_sched_barrier(0);                                      \
} while(0)

#define KPHASE(cc, BUFR, XA, XB, XNA, XNB, DO_NEXT) do {                    \
    if (DO_NEXT) {                                                          \
        STAGE((cc) + 1, ((cc) + 1) & 1);                                    \
        XNA = *(const f32x4*)(xbase + ((cc) + 1) * 32);                     \
        XNB = *(const f32x4*)(xbase + ((cc) + 1) * 32 + 4);                 \
    }                                                                       \
    bf16x8 xh, xm, xl; split8(XA, XB, xh, xm, xl);                          \
    bf16x8 wf[4][3];                                                        \
    _Pragma("unroll")                                                       \
    for (int g_ = 0; g_ < 4; g_++)                                          \
        _Pragma("unroll")                                                   \
        for (int p_ = 0; p_ < 3; p_++)                                      \
            wf[g_][p_] = *(const bf16x8*)((char*)wlds + fb +                \
                           (BUFR) * 12288 + p_ * 4096 + g_ * 256);          \
    _Pragma("unroll")                                                       \
    for (int g_ = 0; g_ < 4; g_++){                                         \
        acc[g_] = MFMA(xh, wf[g_][0], acc[g_], 0, 0, 0);                    \
        acc[g_] = MFMA(xm, wf[g_][0], acc[g_], 0, 0, 0);                    \
        acc[g_] = MFMA(xh, wf[g_][1], acc[g_], 0, 0, 0);                    \
        acc[g_] = MFMA(xm, wf[g_][1], acc[g_], 0, 0, 0);                    \
        acc[g_] = MFMA(xh, wf[g_][2], acc[g_], 0, 0, 0);                    \
        acc[g_] = MFMA(xl, wf[g_][0], acc[g_], 0, 0, 0);                    \
    }                                                                       \
    if (DO_NEXT) {                                                          \
        asm volatile("s_waitcnt vmcnt(2)" ::: "memory");                    \
        __builtin_amdgcn_sched_barrier(0);                                  \
        __builtin_amdgcn_s_barrier();                                       \
    }                                                                       \
} while(0)

    // prologue: stage chunk 0 -> buf0; load x(0); drain stage; barrier
    STAGE(0, 0);
    f32x4 xeA = *(const f32x4*)(xbase);
    f32x4 xeB = *(const f32x4*)(xbase + 4);
    f32x4 xoA, xoB;
    asm volatile("s_waitcnt vmcnt(2)" ::: "memory");
    __builtin_amdgcn_sched_barrier(0);
    __builtin_amdgcn_s_barrier();

    for (int t = 0; t < 32; t++){
        KPHASE(2 * t,     0, xeA, xeB, xoA, xoB, true);
        KPHASE(2 * t + 1, 1, xoA, xoB, xeA, xeB, (t < 31));
    }

    // ---- combine K-halves -> logits LDS ----
    __syncthreads();
    if (wv >= 4){
#pragma unroll
        for (int g = 0; g < 4; g++) red[tg][g][l] = acc[g];
    }
    __syncthreads();
    if (wv < 4){
#pragma unroll
        for (int g = 0; g < 4; g++){
            f32x4 s = acc[g] + red[tg][g][l];
#pragma unroll
            for (int r = 0; r < 4; r++)
                ls[(16 * tg + lk * 4 + r) * 68 + g * 16 + l16] = s[r];
        }
    }
    __syncthreads();

    // ---- epilogue: tid<256, 4 lanes/token (16 experts each) ----
    if (tid < 256){
        const int t = tid >> 2, s4 = tid & 3, eb0 = s4 * 16;
        const float invTemp = (1.0f / 3.0f);
        float m1 = -1e30f, m2 = -1e30f; int i1 = 0, i2 = 0;
        for (int j = 0; j < 16; ++j){
            const int e = eb0 + j;
            float v = (ls[t * 68 + e] + bs[e]) * invTemp;
            ls[t * 68 + e] = v;
            if (v > m1)      { m2 = m1; i2 = i1; m1 = v; i1 = e; }
            else if (v > m2) { m2 = v;  i2 = e; }
        }
#pragma unroll
        for (int off = 1; off <= 2; off <<= 1){
            float om1 = __shfl_xor(m1, off), om2 = __shfl_xor(m2, off);
            int   oi1 = __shfl_xor(i1, off), oi2 = __shfl_xor(i2, off);
            bool sw = (om1 > m1) || (om1 == m1 && oi1 < i1);
            float n1 = sw ? om1 : m1;  int ni1 = sw ? oi1 : i1;
            float lm = sw ? m1  : om1; int li  = sw ? i1  : oi1;
            float w2 = sw ? om2 : m2;  int wi  = sw ? oi2 : i2;
            bool s2 = (lm > w2) || (lm == w2 && li < wi);
            m1 = n1; i1 = ni1;
            m2 = s2 ? lm : w2; i2 = s2 ? li : wi;
        }
        float ssum = 0.f;
        for (int j = 0; j < 16; ++j){
            const int e = eb0 + j;
            float p = __expf(ls[t * 68 + e] - m1);
            ls[t * 68 + e] = p;
            ssum += p;
        }
        ssum += __shfl_xor(ssum, 1);
        ssum += __shfl_xor(ssum, 2);

        float zsq = 0.f;
        if (s4 == 0){
            rs[t] = 1.0f / ssum; ia[t] = i1; ib[t] = i2;
            float p2    = __expf(m2 - m1);
            float inv12 = 1.0f / (1.0f + p2);
            out[(size_t)(tok0 + t) * 2 + 0] = inv12;
            out[(size_t)(tok0 + t) * 2 + 1] = p2 * inv12;
            out[(size_t)NTOK * 2 + (size_t)(tok0 + t) * 2 + 0] = (float)i1;
            out[(size_t)NTOK * 2 + (size_t)(tok0 + t) * 2 + 1] = (float)i2;
            float lse = m1 + logf(ssum);
            zsq = lse * lse;
        }
#pragma unroll
        for (int o = 32; o; o >>= 1) zsq += __shfl_xor(zsq, o);
        if ((tid & 63) == 0) zW[tid >> 6] = zsq;
    }
    __syncthreads();

    // ---- per-expert block partials: lane = expert ----
    if (tid < 64){
        float psum = 0.f, csum = 0.f;
        for (int t2 = 0; t2 < 64; ++t2){
            psum += ls[t2 * 68 + tid] * rs[t2];
            csum += (ia[t2] == tid ? 1.f : 0.f) + (ib[t2] == tid ? 1.f : 0.f);
        }
        part[bid * PS + tid]      = psum;
        part[bid * PS + 64 + tid] = csum;
        if (tid == 0) part[bid * PS + 128] = zW[0] + zW[1] + zW[2] + zW[3];
    }
}

// ---------------------------------------------------------------------------
// Loss reduction over NBLK=256 block partials
// ---------------------------------------------------------------------------
__global__ __launch_bounds__(1024) void moe_gate_loss(
    const float* __restrict__ part, float* __restrict__ out)
{
    __shared__ float spS[16][64], scS[16][64], zW[16];
    const int tid = threadIdx.x;
    const int e = tid & 63, g = tid >> 6;
    float sp = 0.f, sc = 0.f;
    for (int b = g; b < NBLK; b += 16){
        sp += part[b * PS + e];
        sc += part[b * PS + 64 + e];
    }
    spS[g][e] = sp; scS[g][e] = sc;
    float z = (tid < NBLK) ? part[tid * PS + 128] : 0.f;
#pragma unroll
    for (int o = 32; o; o >>= 1) z += __shfl_xor(z, o);
    if ((tid & 63) == 0) zW[g] = z;
    __syncthreads();

    if (tid < 64){
        float tsp = 0.f, tsc = 0.f;
#pragma unroll
        for (int q = 0; q < 16; ++q){ tsp += spS[q][tid]; tsc += scS[q][tid]; }
        float zp = (tid < 16) ? zW[tid] : 0.f;
        const float invN = 1.0f / (float)NTOK;
        float dot = (tsc * invN) * (tsp * invN);
#pragma unroll
        for (int o = 32; o; o >>= 1){
            dot += __shfl_xor(dot, o);
            zp  += __shfl_xor(zp, o);
        }
        if (tid == 0)
            out[(size_t)NTOK * 4] = 0.01f * 64.0f * dot + 1e-4f * zp * invN;
    }
}

// ---------------------------------------------------------------------------
extern "C" void kernel_launch(void* const* d_in, const int* in_sizes, int n_in,
                              void* d_out, int out_size, void* d_ws, size_t ws_size,
                              hipStream_t stream)
{
    const float* x    = (const float*)d_in[0];
    const float* gw   = (const float*)d_in[1];
    const float* bias = (const float*)d_in[2];
    float* out = (float*)d_out;

    short* wpl  = (short*)d_ws;                                      // 1.5 MB
    float* part = (float*)((char*)d_ws + 3 * PLANE * sizeof(short)); // 135 KB

    moe_wsplit<<<128, 256, 0, stream>>>(gw, wpl);
    moe_gate_main<<<NBLK, 512, 0, stream>>>(x, wpl, bias, out, part);
    moe_gate_loss<<<1, 1024, 0, stream>>>(part, out);
}